// Round 11
// baseline (707.747 us; speedup 1.0000x reference)
//
#include <hip/hip_runtime.h>
#include <math.h>

#define B_ 2
#define T_ 4096
#define D_ 2048
#define H_ 16
#define DK 128
#define DV 128
#define CH 64
#define M_ (B_ * T_)  // 8192
#define NCH (T_ / CH) // 64 chunks

typedef __attribute__((ext_vector_type(8))) short bfrag;   // 8 bf16
typedef __attribute__((ext_vector_type(4))) float ffrag;   // 4 f32 acc
typedef __attribute__((ext_vector_type(8))) unsigned short u16x8;
typedef unsigned short us;

#define MFMA __builtin_amdgcn_mfma_f32_16x16x32_bf16

__device__ inline us f2bf(float f) {
  union { float f; unsigned u; } v; v.f = f;
  unsigned r = v.u + 0x7fffu + ((v.u >> 16) & 1u);
  return (us)(r >> 16);
}
__device__ inline float bf2f(us u) {
  union { unsigned u; float f; } v; v.u = ((unsigned)u) << 16;
  return v.f;
}

// async global->LDS, 16B per lane (dest = wave-uniform base + lane*16)
__device__ inline void gl_lds16(const us* g, us* l) {
  __builtin_amdgcn_global_load_lds(
      (const __attribute__((address_space(1))) void*)g,
      (__attribute__((address_space(3))) void*)l, 16, 0, 0);
}

// ---------------------------------------------------------------------------
// x_prep: fused f32->bf16 convert of x + beta = sigmoid(x @ Wb) -> betaT[bh][T]
// one block per row; x read once.
// ---------------------------------------------------------------------------
__global__ __launch_bounds__(256) void x_prep(const float* __restrict__ x,
                                              const float* __restrict__ Wb,
                                              us* __restrict__ xb,
                                              float* __restrict__ betaT) {
  __shared__ float red[4][16];
  const int m = blockIdx.x, t = threadIdx.x;
  const int lane = t & 63, w = t >> 6;
  const int d0 = t * 8;
  const float* xr = x + (size_t)m * D_ + d0;
  float v[8];
  *reinterpret_cast<float4*>(&v[0]) = *reinterpret_cast<const float4*>(xr);
  *reinterpret_cast<float4*>(&v[4]) = *reinterpret_cast<const float4*>(xr + 4);
  ushort4 o0, o1;
  o0.x = f2bf(v[0]); o0.y = f2bf(v[1]); o0.z = f2bf(v[2]); o0.w = f2bf(v[3]);
  o1.x = f2bf(v[4]); o1.y = f2bf(v[5]); o1.z = f2bf(v[6]); o1.w = f2bf(v[7]);
  us* xo = xb + (size_t)m * D_ + d0;
  *reinterpret_cast<ushort4*>(xo) = o0;
  *reinterpret_cast<ushort4*>(xo + 4) = o1;

  float p[16];
#pragma unroll
  for (int h = 0; h < 16; ++h) p[h] = 0.f;
#pragma unroll
  for (int j = 0; j < 8; ++j) {
    const float* wr = Wb + (size_t)(d0 + j) * H_;
    const float4 w0 = *reinterpret_cast<const float4*>(wr);
    const float4 w1 = *reinterpret_cast<const float4*>(wr + 4);
    const float4 w2 = *reinterpret_cast<const float4*>(wr + 8);
    const float4 w3 = *reinterpret_cast<const float4*>(wr + 12);
    const float xv = v[j];
    p[0] = fmaf(xv, w0.x, p[0]);  p[1] = fmaf(xv, w0.y, p[1]);
    p[2] = fmaf(xv, w0.z, p[2]);  p[3] = fmaf(xv, w0.w, p[3]);
    p[4] = fmaf(xv, w1.x, p[4]);  p[5] = fmaf(xv, w1.y, p[5]);
    p[6] = fmaf(xv, w1.z, p[6]);  p[7] = fmaf(xv, w1.w, p[7]);
    p[8] = fmaf(xv, w2.x, p[8]);  p[9] = fmaf(xv, w2.y, p[9]);
    p[10] = fmaf(xv, w2.z, p[10]); p[11] = fmaf(xv, w2.w, p[11]);
    p[12] = fmaf(xv, w3.x, p[12]); p[13] = fmaf(xv, w3.y, p[13]);
    p[14] = fmaf(xv, w3.z, p[14]); p[15] = fmaf(xv, w3.w, p[15]);
  }
#pragma unroll
  for (int off = 1; off < 64; off <<= 1)
#pragma unroll
    for (int h = 0; h < 16; ++h) p[h] += __shfl_xor(p[h], off);
  if (lane == 0)
#pragma unroll
    for (int h = 0; h < 16; ++h) red[w][h] = p[h];
  __syncthreads();
  if (t < 16) {
    const float s = red[0][t] + red[1][t] + red[2][t] + red[3][t];
    const int b = m >> 12, tt = m & (T_ - 1);
    betaT[((size_t)(b * H_ + t)) * T_ + tt] = 1.f / (1.f + expf(-s));
  }
}

// ---------------------------------------------------------------------------
// transpose + convert: Wt[n][k] = bf16(W[k][n]), 64x64 tiles
// ---------------------------------------------------------------------------
__global__ __launch_bounds__(256) void wtrans(const float* __restrict__ W,
                                              us* __restrict__ Wt) {
  __shared__ float tile[64][68];
  const int k0 = blockIdx.y * 64, n0 = blockIdx.x * 64;
  const int lr = threadIdx.x >> 4, lc = (threadIdx.x & 15) * 4;
#pragma unroll
  for (int p = 0; p < 4; ++p) {
    const int r = lr + p * 16;
    *reinterpret_cast<float4*>(&tile[r][lc]) =
        *reinterpret_cast<const float4*>(&W[(size_t)(k0 + r) * D_ + n0 + lc]);
  }
  __syncthreads();
#pragma unroll
  for (int p = 0; p < 4; ++p) {
    const int r = lr + p * 16;
    ushort4 o;
    o.x = f2bf(tile[lc + 0][r]); o.y = f2bf(tile[lc + 1][r]);
    o.z = f2bf(tile[lc + 2][r]); o.w = f2bf(tile[lc + 3][r]);
    *reinterpret_cast<ushort4*>(&Wt[(size_t)(n0 + r) * D_ + k0 + lc]) = o;
  }
}

// ---------------------------------------------------------------------------
// gemm256 v2 (proven R9): C[M,N] = A[M,K] @ Bt[N,K]^T (bf16).
// ---------------------------------------------------------------------------
template <bool OUTF32>
__global__ __launch_bounds__(512, 2) void gemm256(const us* __restrict__ A,
                                                  const us* __restrict__ Bt,
                                                  void* __restrict__ Cp,
                                                  int M, int N, int K) {
  __shared__ __align__(16) us lds[2][2][2][256 * 32];  // 128 KiB
  const int t = threadIdx.x, l = t & 63, w = t >> 6;
  const int wm = w >> 2, wn = w & 3;           // 2 x 4 waves
  const int fr = l & 15, hi = l >> 4;
  const int sx = 8 * (hi ^ ((fr >> 1) & 3));   // swizzled frag slot (bf16 units)

  const int m0 = blockIdx.y * 256;
  const int n0 = blockIdx.x * 256;             // XCD stripe (x dim == 8)

  const int srow = t >> 2;
  const int scol = 8 * ((t & 3) ^ ((t >> 3) & 3));
  const us* Ab = A + (size_t)(m0 + srow) * K + scol;
  const us* Bb = Bt + (size_t)(n0 + srow) * K + scol;

  ffrag acc[8][4];
#pragma unroll
  for (int mi = 0; mi < 8; ++mi)
#pragma unroll
    for (int ni = 0; ni < 4; ++ni)
#pragma unroll
      for (int e = 0; e < 4; ++e) acc[mi][ni][e] = 0.f;

#define STG_A(bf, kk, kt)                                                      \
  do {                                                                         \
    gl_lds16(Ab + (size_t)(kt) * 64 + (kk) * 32, &lds[bf][0][kk][t * 8]);      \
    gl_lds16(Ab + (size_t)128 * K + (size_t)(kt) * 64 + (kk) * 32,             \
             &lds[bf][0][kk][4096 + t * 8]);                                   \
  } while (0)
#define STG_B(bf, kk, kt)                                                      \
  do {                                                                         \
    gl_lds16(Bb + (size_t)(kt) * 64 + (kk) * 32, &lds[bf][1][kk][t * 8]);      \
    gl_lds16(Bb + (size_t)128 * K + (size_t)(kt) * 64 + (kk) * 32,             \
             &lds[bf][1][kk][4096 + t * 8]);                                   \
  } while (0)

  const int NT = K >> 6;
  STG_A(0, 0, 0); STG_B(0, 0, 0); STG_A(0, 1, 0); STG_B(0, 1, 0);
  asm volatile("s_waitcnt vmcnt(4)" ::: "memory");
  __builtin_amdgcn_s_barrier();
  __builtin_amdgcn_sched_barrier(0);

  const int arow = wm * 128 + fr;
  const int brow = wn * 64 + fr;

#pragma unroll 1
  for (int kt = 0; kt < NT; ++kt) {
    const int cur = kt & 1, oth = cur ^ 1;
    const bool pf = (kt + 1 < NT);
    bfrag af4[4], bf4[4];

    // ======== kk = 0 ========
    {
      const us* pa = &lds[cur][0][0][0];
      const us* pb = &lds[cur][1][0][0];
#pragma unroll
      for (int ni = 0; ni < 4; ++ni)
        bf4[ni] = *reinterpret_cast<const bfrag*>(pb + (brow + ni * 16) * 32 + sx);
#pragma unroll
      for (int mi = 0; mi < 4; ++mi)
        af4[mi] = *reinterpret_cast<const bfrag*>(pa + (arow + mi * 16) * 32 + sx);
      if (pf) STG_A(oth, 0, kt + 1);
      __builtin_amdgcn_s_setprio(1);
#pragma unroll
      for (int mi = 0; mi < 4; ++mi)
#pragma unroll
        for (int ni = 0; ni < 4; ++ni)
          acc[mi][ni] = MFMA(af4[mi], bf4[ni], acc[mi][ni], 0, 0, 0);
      __builtin_amdgcn_s_setprio(0);
#pragma unroll
      for (int mi = 0; mi < 4; ++mi)
        af4[mi] = *reinterpret_cast<const bfrag*>(pa + (arow + 64 + mi * 16) * 32 + sx);
      if (pf) STG_B(oth, 0, kt + 1);
      __builtin_amdgcn_s_setprio(1);
#pragma unroll
      for (int mi = 0; mi < 4; ++mi)
#pragma unroll
        for (int ni = 0; ni < 4; ++ni)
          acc[mi + 4][ni] = MFMA(af4[mi], bf4[ni], acc[mi + 4][ni], 0, 0, 0);
      __builtin_amdgcn_s_setprio(0);
    }
    if (pf) asm volatile("s_waitcnt vmcnt(4)" ::: "memory");
    else    asm volatile("s_waitcnt vmcnt(0)" ::: "memory");
    __builtin_amdgcn_s_barrier();
    __builtin_amdgcn_sched_barrier(0);

    // ======== kk = 1 ========
    {
      const us* pa = &lds[cur][0][1][0];
      const us* pb = &lds[cur][1][1][0];
#pragma unroll
      for (int ni = 0; ni < 4; ++ni)
        bf4[ni] = *reinterpret_cast<const bfrag*>(pb + (brow + ni * 16) * 32 + sx);
#pragma unroll
      for (int mi = 0; mi < 4; ++mi)
        af4[mi] = *reinterpret_cast<const bfrag*>(pa + (arow + mi * 16) * 32 + sx);
      if (pf) STG_A(oth, 1, kt + 1);
      __builtin_amdgcn_s_setprio(1);
#pragma unroll
      for (int mi = 0; mi < 4; ++mi)
#pragma unroll
        for (int ni = 0; ni < 4; ++ni)
          acc[mi][ni] = MFMA(af4[mi], bf4[ni], acc[mi][ni], 0, 0, 0);
      __builtin_amdgcn_s_setprio(0);
#pragma unroll
      for (int mi = 0; mi < 4; ++mi)
        af4[mi] = *reinterpret_cast<const bfrag*>(pa + (arow + 64 + mi * 16) * 32 + sx);
      if (pf) STG_B(oth, 1, kt + 1);
      __builtin_amdgcn_s_setprio(1);
#pragma unroll
      for (int mi = 0; mi < 4; ++mi)
#pragma unroll
        for (int ni = 0; ni < 4; ++ni)
          acc[mi + 4][ni] = MFMA(af4[mi], bf4[ni], acc[mi + 4][ni], 0, 0, 0);
      __builtin_amdgcn_s_setprio(0);
    }
    if (pf) asm volatile("s_waitcnt vmcnt(4)" ::: "memory");
    else    asm volatile("s_waitcnt vmcnt(0)" ::: "memory");
    __builtin_amdgcn_s_barrier();
    __builtin_amdgcn_sched_barrier(0);
  }
#undef STG_A
#undef STG_B

  const int crow = m0 + wm * 128 + hi * 4;
  const int ccol = n0 + wn * 64 + fr;
#pragma unroll
  for (int mi = 0; mi < 8; ++mi)
#pragma unroll
    for (int ni = 0; ni < 4; ++ni)
#pragma unroll
      for (int j = 0; j < 4; ++j) {
        const size_t idx = (size_t)(crow + mi * 16 + j) * N + ccol + ni * 16;
        if constexpr (OUTF32) ((float*)Cp)[idx] = acc[mi][ni][j];
        else ((us*)Cp)[idx] = f2bf(acc[mi][ni][j]);
      }
}

// ---------------------------------------------------------------------------
// conv+silu bodies
// ---------------------------------------------------------------------------
__device__ inline void conv_body(const us* __restrict__ in, const float* cw,
                                 int bt, int d0, int mode, float v[8]) {
  const int tb = bt & (T_ - 1);
  const us* row = in + (size_t)bt * D_ + d0;
#pragma unroll
  for (int j = 0; j < 8; ++j) v[j] = 0.f;
#pragma unroll
  for (int j = 0; j < 4; ++j) {
    if (tb >= j) {
      const us* rp = row - (size_t)(j * D_);
      const ushort4 a = *reinterpret_cast<const ushort4*>(rp);
      const ushort4 b = *reinterpret_cast<const ushort4*>(rp + 4);
      const float wj = cw[3 - j];
      v[0] = fmaf(wj, bf2f(a.x), v[0]); v[1] = fmaf(wj, bf2f(a.y), v[1]);
      v[2] = fmaf(wj, bf2f(a.z), v[2]); v[3] = fmaf(wj, bf2f(a.w), v[3]);
      v[4] = fmaf(wj, bf2f(b.x), v[4]); v[5] = fmaf(wj, bf2f(b.y), v[5]);
      v[6] = fmaf(wj, bf2f(b.z), v[6]); v[7] = fmaf(wj, bf2f(b.w), v[7]);
    }
  }
#pragma unroll
  for (int j = 0; j < 8; ++j) v[j] = v[j] / (1.f + expf(-v[j]));
  if (mode) {
    float ss = 0.f;
#pragma unroll
    for (int j = 0; j < 8; ++j) ss = fmaf(v[j], v[j], ss);
    ss += __shfl_xor(ss, 1);
    ss += __shfl_xor(ss, 2);
    ss += __shfl_xor(ss, 4);
    ss += __shfl_xor(ss, 8);
    float sc = rsqrtf(ss + 1e-6f);
    if (mode == 2) sc *= 0.08838834764831845f;  // 128^-0.5
#pragma unroll
    for (int j = 0; j < 8; ++j) v[j] *= sc;
  }
}

__global__ __launch_bounds__(256) void conv_silu_plain(const us* __restrict__ in,
                                                       const float* __restrict__ cw,
                                                       us* __restrict__ out) {
  const int bt = blockIdx.x, d0 = threadIdx.x * 8;
  float v[8];
  conv_body(in, cw, bt, d0, 0, v);
  ushort4 o0, o1;
  o0.x = f2bf(v[0]); o0.y = f2bf(v[1]); o0.z = f2bf(v[2]); o0.w = f2bf(v[3]);
  o1.x = f2bf(v[4]); o1.y = f2bf(v[5]); o1.z = f2bf(v[6]); o1.w = f2bf(v[7]);
  us* op = out + (size_t)bt * D_ + d0;
  *reinterpret_cast<ushort4*>(op) = o0;
  *reinterpret_cast<ushort4*>(op + 4) = o1;
}

// conv+silu+l2norm -> swizzled chunk layout [bh][cid][64][128], 16B-group XOR(r&15)
__global__ __launch_bounds__(256) void conv_silu_chunk(const us* __restrict__ in,
                                                       const float* __restrict__ cw,
                                                       us* __restrict__ out,
                                                       int mode) {
  const int bt = blockIdx.x, d0 = threadIdx.x * 8;
  float v[8];
  conv_body(in, cw, bt, d0, mode, v);
  const int b = bt >> 12, tt = bt & (T_ - 1);
  const int cid = tt >> 6, r = tt & 63;
  const int h = d0 >> 7, g = (d0 & 127) >> 3;
  us* dst = out + ((size_t)((b * H_ + h) * NCH + cid)) * (CH * DK) +
            r * 128 + ((g ^ (r & 15)) * 8);
  ushort4 o0, o1;
  o0.x = f2bf(v[0]); o0.y = f2bf(v[1]); o0.z = f2bf(v[2]); o0.w = f2bf(v[3]);
  o1.x = f2bf(v[4]); o1.y = f2bf(v[5]); o1.z = f2bf(v[6]); o1.w = f2bf(v[7]);
  *reinterpret_cast<ushort4*>(dst) = o0;
  *reinterpret_cast<ushort4*>(dst + 4) = o1;
}

// ---------------------------------------------------------------------------
// f32 blocked product step for T = M^-1
// ---------------------------------------------------------------------------
__device__ inline void prod_step(float* Tf, const float* Am, float* xbuf,
                                 int r, int c, int I, int J,
                                 int nk, int K0, int K1, int K2) {
  float X = 0.f;
  const int Ks[3] = {K0, K1, K2};
  for (int kk = 0; kk < nk; ++kk) {
    const int K = Ks[kk];
    const float* amrow = Am + (16 * I + r) * 72 + 16 * K;
    const float* tcol = Tf + (16 * K) * 68 + 16 * J + c;
#pragma unroll
    for (int m = 0; m < 16; ++m) X = fmaf(amrow[m], tcol[m * 68], X);
  }
  __syncthreads();
  xbuf[r * 17 + c] = X;
  __syncthreads();
  float s = 0.f;
  const float* trow = Tf + (16 * I + r) * 68 + 16 * I;
#pragma unroll
  for (int m = 0; m < 16; ++m) s = fmaf(trow[m], xbuf[m * 17 + c], s);
  Tf[(16 * I + r) * 68 + 16 * J + c] = -s;
  __syncthreads();
}

// ---------------------------------------------------------------------------
// delta_prep v2 (proven R6): block per (b,h,chunk) = 2048, 256 thr, 2 blocks/CU.
// ---------------------------------------------------------------------------
__global__ __launch_bounds__(256, 2) void delta_prep(const us* __restrict__ qch,
                                                     const us* __restrict__ kch,
                                                     const float* __restrict__ betaT,
                                                     us* __restrict__ v_uv,
                                                     us* __restrict__ Wout,
                                                     us* __restrict__ kTout,
                                                     us* __restrict__ Aout) {
  __shared__ __align__(16) unsigned char lds[72000];
  us*    ks    = (us*)(lds);             // [64*128] swz     (P0-P1)
  us*    Tb    = (us*)(lds);             // [64][72] bf16    (P5-)
  float* Am    = (float*)(lds + 16384);  // [64][72] f32     (P1-P4)
  us*    vTb   = (us*)(lds + 16384);     // [128][72] bf16   (P5-)
  float* Tf    = (float*)(lds + 34816);  // [64][68] f32     (P2-P5)
  us*    atst  = (us*)(lds + 34816);     // attn stage [64*64] (P0-P2)
  us*    Wst   = (us*)(lds + 34816);     // W stage [64*128] (P6-)
  us*    kTb   = (us*)(lds + 52224);     // [128][72] bf16   (P1-P6a)
  us*    UVst  = (us*)(lds + 52224);     // [64*128]         (P6b-)
  float* betac = (float*)(lds + 70656);  // [64]
  float* xbuf  = (float*)(lds + 70912);  // [16][17]

  const int t = threadIdx.x, w = t >> 6, l = t & 63;
  const int rr = l & 15, hi = l >> 4;
  const int bx = blockIdx.x;
  const int bh = bx >> 6, cid = bx & 63;
  const int b = bh >> 4, h = bh & 15;
  const size_t rowbase = ((size_t)b * T_ + (size_t)cid * CH) * D_ + (size_t)h * DK;
  const size_t cbase = (size_t)bx * (CH * DK);
  const size_t abase = (size_t)bx * (CH * CH);

  // ---- P0
  {
    const us* kg = kch + cbase;
#pragma unroll
    for (int p = 0; p < 4; ++p)
      gl_lds16(kg + p * 2048 + t * 8, ks + p * 2048 + t * 8);
    const float4 z = make_float4(0.f, 0.f, 0.f, 0.f);
    *reinterpret_cast<float4*>(atst + t * 16) = z;
    *reinterpret_cast<float4*>(atst + t * 16 + 8) = z;
    if (t < 64) betac[t] = betaT[(size_t)bh * T_ + cid * CH + t];
  }
  __syncthreads();

  // ---- P1
  {
    bfrag qf[4], kf[4];
#pragma unroll
    for (int k4 = 0; k4 < 4; ++k4) {
      const int go = ((4 * k4 + hi) ^ rr) * 8;
      qf[k4] = *reinterpret_cast<const bfrag*>(qch + cbase + (16 * w + rr) * 128 + go);
      kf[k4] = *reinterpret_cast<const bfrag*>(ks + (16 * w + rr) * 128 + go);
    }
    for (int jt = 0; jt <= w; ++jt) {
      ffrag accA = {0.f, 0.f, 0.f, 0.f}, accQ = {0.f, 0.f, 0.f, 0.f};
#pragma unroll
      for (int k4 = 0; k4 < 4; ++k4) {
        const bfrag bfr = *reinterpret_cast<const bfrag*>(
            ks + (16 * jt + rr) * 128 + (((4 * k4 + hi) ^ rr) * 8));
        accA = MFMA(kf[k4], bfr, accA, 0, 0, 0);
        accQ = MFMA(qf[k4], bfr, accQ, 0, 0, 0);
      }
#pragma unroll
      for (int j4 = 0; j4 < 4; ++j4) {
        const int i = 16 * w + 4 * hi + j4, j = 16 * jt + rr;
        Am[i * 72 + j] = (j < i) ? betac[i] * accA[j4] : 0.f;
        if (j <= i)
          atst[i * 64 + (((j >> 3) ^ (i & 7)) * 8) + (j & 7)] = f2bf(accQ[j4]);
      }
    }
    const int r = t & 63, part = t >> 6;
#pragma unroll
    for (int gi = 0; gi < 4; ++gi) {
      const int g = 4 * part + gi;
      const u16x8 kv = *reinterpret_cast<const u16x8*>(ks + r * 128 + ((g ^ (r & 15)) * 8));
#pragma unroll
      for (int j = 0; j < 8; ++j) kTb[(g * 8 + j) * 72 + r] = kv[j];
    }
  }
  __syncthreads();

  // ---- P2
  {
#pragma unroll
    for (int p = 0; p < 2; ++p) {
      const int unit = t + p * 256;
      *reinterpret_cast<u16x8*>(Aout + abase + unit * 8) =
          *reinterpret_cast<const u16x8*>(atst + unit * 8);
    }
#pragma unroll
    for (int p = 0; p < 4; ++p) {
      const int unit = t + p * 256;
      const int d = unit >> 3, sg = unit & 7;
      *reinterpret_cast<u16x8*>(kTout + cbase + unit * 8) =
          *reinterpret_cast<const u16x8*>(kTb + d * 72 + ((sg ^ (d & 7)) * 8));
    }
  }
  __syncthreads();
  for (int i = t; i < 64 * 68; i += 256) Tf[i] = 0.f;
  __syncthreads();

  // ---- P3
  if (t < 64) {
    const int blk = t >> 4, j = t & 15, bd = blk * 16;
    Tf[(bd + j) * 68 + bd + j] = 1.f;
    for (int i = j + 1; i < 16; ++i) {
      float s = 0.f;
      for (int m = j; m < i; ++m)
        s = fmaf(Am[(bd + i) * 72 + bd + m], Tf[(bd + m) * 68 + bd + j], s);
      Tf[(bd + i) * 68 + bd + j] = -s;
    }
  }
  __syncthreads();

  // ---- P4
  {
    const int r = t >> 4, c = t & 15;
    prod_step(Tf, Am, xbuf, r, c, 1, 0, 1, 0, 0, 0);
    prod_step(Tf, Am, xbuf, r, c, 2, 0, 2, 0, 1, 0);
    prod_step(Tf, Am, xbuf, r, c, 3, 0, 3, 0, 1, 2);
    prod_step(Tf, Am, xbuf, r, c, 2, 1, 1, 1, 0, 0);
    prod_step(Tf, Am, xbuf, r, c, 3, 1, 2, 1, 2, 0);
    prod_step(Tf, Am, xbuf, r, c, 3, 2, 1, 2, 0, 0);
  }

  // ---- P5
  {
    const int vr = t >> 2, vp = t & 3;
    u16x8 vv[4];
#pragma unroll
    for (int g = 0; g < 4; ++g)
      vv[g] = *reinterpret_cast<const u16x8*>(v_uv + rowbase + (size_t)vr * D_ +
                                              vp * 32 + g * 8);
    const int ti = t >> 2, tg = t & 3;
    u16x8 w0, w1;
#pragma unroll
    for (int jj = 0; jj < 8; ++jj) {
      const int j0 = tg * 16 + jj, j1 = j0 + 8;
      w0[jj] = f2bf(Tf[ti * 68 + j0] * betac[j0]);
      w1[jj] = f2bf(Tf[ti * 68 + j1] * betac[j1]);
    }
    *reinterpret_cast<u16x8*>(Tb + ti * 72 + tg * 16) = w0;
    *reinterpret_cast<u16x8*>(Tb + ti * 72 + tg * 16 + 8) = w1;
#pragma unroll
    for (int g = 0; g < 4; ++g)
#pragma unroll
      for (int j = 0; j < 8; ++j)
        vTb[(vp * 32 + g * 8 + j) * 72 + vr] = vv[g][j];
  }
  __syncthreads();

  // ---- P6a
  {
    bfrag ta[2];
#pragma unroll
    for (int k2 = 0; k2 < 2; ++k2)
      ta[k2] = *reinterpret_cast<const bfrag*>(Tb + (16 * w + rr) * 72 + 32 * k2 + 8 * hi);
#pragma unroll
    for (int dt = 0; dt < 8; ++dt) {
      ffrag acc = {0.f, 0.f, 0.f, 0.f};
#pragma unroll
      for (int k2 = 0; k2 < 2; ++k2) {
        const bfrag bfr = *reinterpret_cast<const bfrag*>(
            kTb + (16 * dt + rr) * 72 + 32 * k2 + 8 * hi);
        acc = MFMA(ta[k2], bfr, acc, 0, 0, 0);
      }
#pragma unroll
      for (int j4 = 0; j4 < 4; ++j4) {
        const int i = 16 * w + 4 * hi + j4, d = 16 * dt + rr;
        Wst[i * 128 + (((d >> 3) ^ (i & 15)) * 8) + (d & 7)] = f2bf(-acc[j4]);
      }
    }
  }
  __syncthreads();

  // ---- P6b
  {
    bfrag ta[2];
#pragma unroll
    for (int k2 = 0; k2 < 2; ++k2)
      ta[k2] = *reinterpret_cast<const bfrag*>(Tb + (16 * w + rr) * 72 + 32 * k2 + 8 * hi);
#pragma unroll
    for (int et = 0; et < 8; ++et) {
      ffrag acc = {0.f, 0.f, 0.f, 0.f};
#pragma unroll
      for (int k2 = 0; k2 < 2; ++k2) {
        const bfrag bfr = *reinterpret_cast<const bfrag*>(
            vTb + (16 * et + rr) * 72 + 32 * k2 + 8 * hi);
        acc = MFMA(ta[k2], bfr, acc, 0, 0, 0);
      }
#pragma unroll
      for (int j4 = 0; j4 < 4; ++j4)
        UVst[(16 * w + 4 * hi + j4) * 128 + 16 * et + rr] = f2bf(acc[j4]);
    }
#pragma unroll
    for (int p = 0; p < 4; ++p) {
      const int unit = t + p * 256;
      *reinterpret_cast<u16x8*>(Wout + cbase + unit * 8) =
          *reinterpret_cast<const u16x8*>(Wst + unit * 8);
    }
  }
  __syncthreads();

  // ---- P7
#pragma unroll
  for (int p = 0; p < 4; ++p) {
    const int unit = t + p * 256;
    const int r = unit >> 4, g = unit & 15;
    *reinterpret_cast<u16x8*>(v_uv + rowbase + (size_t)r * D_ + g * 8) =
        *reinterpret_cast<const u16x8*>(UVst + r * 128 + g * 8);
  }
}

// ---------------------------------------------------------------------------
// delta_seq v4: 512 thr (8 waves, 2/SIMD), role-split phases, coalesced o.
// waves 0-3: phase A = u (4 MFMA); phase B = S-update (4 MFMA, reg-resident S)
// waves 4-7: phase A = q.Sb (4 MFMA); phase B = +attn.u (1-2 MFMA) -> ob LDS
// o written coalesced at top of next chunk. Counted-vmcnt staging as v3.
// ---------------------------------------------------------------------------
__global__ __launch_bounds__(512, 1) void delta_seq(const us* __restrict__ qch,
                                                    const us* __restrict__ Wch,
                                                    const us* __restrict__ kTch,
                                                    const us* __restrict__ atch,
                                                    us* __restrict__ uv_o) {
  __shared__ __align__(16) us qs[2][CH * DK];    // 16KB x2
  __shared__ __align__(16) us Ws[2][CH * DK];    // 16KB x2
  __shared__ __align__(16) us kTs[2][DK * CH];   // 16KB x2
  __shared__ __align__(16) us ats[2][CH * CH];   // 8KB  x2
  __shared__ __align__(16) us uvs[2][CH * 16];   // 2KB  x2
  __shared__ __align__(16) us Sb[2][16 * 136];   // 4.25KB x2 (S^T bf16, dbuf)
  __shared__ __align__(16) us ub[CH * 18];       // 2.25KB (u bf16)
  __shared__ __align__(16) us ob[CH * 18];       // 2.25KB (o bf16 stage)

  const int t = threadIdx.x, l = t & 63, w = t >> 6;
  const int bx = blockIdx.x;
  const int vs = bx >> 5, bh = bx & 31;
  const int b = bh >> 4, h = bh & 15;
  const int rr = l & 15, hi = l >> 4;
  const int w2 = w & 3;  // tile index within role group

  // S registers (waves 0-3 only use them): wave w owns tiles 2w, 2w+1
  ffrag sacc[2];
#pragma unroll
  for (int t2 = 0; t2 < 2; ++t2)
#pragma unroll
    for (int j = 0; j < 4; ++j) sacc[t2][j] = 0.f;

  for (int i = t; i < 16 * 136; i += 512) Sb[0][i] = 0;

  const size_t cbQ = (size_t)(bh * NCH) * (CH * DK);
  const size_t cbA = (size_t)(bh * NCH) * (CH * CH);
  const size_t rowbase0 = ((size_t)b * T_) * D_ + (size_t)h * DK + vs * 16;

#define STAGE(buf, cid)                                                        \
  do {                                                                         \
    const us* qg = qch + cbQ + (size_t)(cid) * (CH * DK);                      \
    const us* Wg = Wch + cbQ + (size_t)(cid) * (CH * DK);                      \
    const us* kg = kTch + cbQ + (size_t)(cid) * (CH * DK);                     \
    const us* ag = atch + cbA + (size_t)(cid) * (CH * CH);                     \
    gl_lds16(qg + t * 8, &qs[buf][t * 8]);                                     \
    gl_lds16(qg + 4096 + t * 8, &qs[buf][4096 + t * 8]);                       \
    gl_lds16(Wg + t * 8, &Ws[buf][t * 8]);                                     \
    gl_lds16(Wg + 4096 + t * 8, &Ws[buf][4096 + t * 8]);                       \
    gl_lds16(kg + t * 8, &kTs[buf][t * 8]);                                    \
    gl_lds16(kg + 4096 + t * 8, &kTs[buf][4096 + t * 8]);                      \
    gl_lds16(ag + t * 8, &ats[buf][t * 8]);                                    \
    if (t < 128)                                                               \
      gl_lds16(uv_o + rowbase0 + (size_t)((cid) * CH + (t >> 1)) * D_ + (t & 1) * 8, \
               &uvs[buf][t * 8]);                                              \
  } while (0)

  STAGE(0, 0);
  asm volatile("s_waitcnt vmcnt(0) lgkmcnt(0)" ::: "memory");
  __builtin_amdgcn_s_barrier();
  __builtin_amdgcn_sched_barrier(0);

  for (int cid = 0; cid < NCH; ++cid) {
    const int cur = cid & 1;

    // coalesced copy-out of previous chunk's o (ob stable until phase B)
    if (cid > 0 && t < 128) {
      const u16x8 ov = *reinterpret_cast<const u16x8*>(&ob[(t >> 1) * 18 + (t & 1) * 8]);
      *reinterpret_cast<u16x8*>(uv_o + rowbase0 +
          (size_t)((cid - 1) * CH + (t >> 1)) * D_ + (t & 1) * 8) = ov;
    }
    if (cid + 1 < NCH) STAGE(cur ^ 1, cid + 1);  // async; drained at end barrier

    bfrag sbf[4];
#pragma unroll
    for (int ks = 0; ks < 4; ++ks)
      sbf[ks] = *reinterpret_cast<const bfrag*>(&Sb[cur][rr * 136 + ks * 32 + hi * 8]);

    ffrag acc4;
    if (w < 4) {
      // ---- phase A (u): rows 16w..16w+15
#pragma unroll
      for (int j = 0; j < 4; ++j)
        acc4[j] = bf2f(uvs[cur][(16 * w + 4 * hi + j) * 16 + rr]);
#pragma unroll
      for (int ks = 0; ks < 4; ++ks) {
        const bfrag af = *reinterpret_cast<const bfrag*>(
            &Ws[cur][(16 * w + rr) * 128 + (((4 * ks + hi) ^ rr) * 8)]);
        acc4 = MFMA(af, sbf[ks], acc4, 0, 0, 0);
      }
#pragma unroll
      for (int j = 0; j < 4; ++j)
        ub[(16 * w + 4 * hi + j) * 18 + rr] = f2bf(acc4[j]);
    } else {
      // ---- phase A (o partial = q.Sb): rows 16w2..16w2+15
#pragma unroll
      for (int j = 0; j < 4; ++j) acc4[j] = 0.f;
#pragma unroll
      for (int ks = 0; ks < 4; ++ks) {
        const bfrag af = *reinterpret_cast<const bfrag*>(
            &qs[cur][(16 * w2 + rr) * 128 + (((4 * ks + hi) ^ rr) * 8)]);
        acc4 = MFMA(af, sbf[ks], acc4, 0, 0, 0);
      }
    }
    asm volatile("s_waitcnt lgkmcnt(0)" ::: "memory");  // ub visible; VM loads in flight
    __builtin_amdgcn_s_barrier();
    __builtin_amdgcn_sched_barrier(0);

    if (w < 4) {
      // ---- phase B (S-update): tiles 2w, 2w+1
      bfrag ubf[2];
#pragma unroll
      for (int ks = 0; ks < 2; ++ks)
#pragma unroll
        for (int j = 0; j < 8; ++j)
          ubf[ks][j] = (short)ub[(32 * ks + 8 * hi + j) * 18 + rr];
#pragma unroll
      for (int t2 = 0; t2 < 2; ++t2) {
        const int tile = 2 * w + t2;
#pragma unroll
        for (int ks = 0; ks < 2; ++ks) {
          const bfrag af = *reinterpret_cast<const bfrag*>(
              &kTs[cur][(16 * tile + rr) * 64 + (((4 * ks + hi) ^ (rr & 7)) * 8)]);
          sacc[t2] = MFMA(af, ubf[ks], sacc[t2], 0, 0, 0);
        }
        ushort4 sw;
        sw.x = f2bf(sacc[t2][0]); sw.y = f2bf(sacc[t2][1]);
        sw.z = f2bf(sacc[t2][2]); sw.w = f2bf(sacc[t2][3]);
        *reinterpret_cast<ushort4*>(&Sb[cur ^ 1][rr * 136 + 16 * tile + 4 * hi]) = sw;
      }
    } else {
      // ---- phase B (o finish = + attn.u): rows 16w2..16w2+15
      const int nks = (w2 < 2) ? 1 : 2;  // causal: upper attn cols are zero
      for (int ks = 0; ks < nks; ++ks) {
        bfrag ubf;
#pragma unroll
        for (int j = 0; j < 8; ++j)
          ubf[j] = (short)ub[(32 * ks + 8 * hi + j) * 18 + rr];
        const bfrag af = *reinterpret_cast<const bfrag*>(
            &ats[cur][(16 * w2 + rr) * 64 + (((4 * ks + hi) ^ (rr & 7)) * 8)]);
        acc4 = MFMA(af, ubf, acc4, 0, 0, 0);
      }
#pragma unroll
      for (int j = 0; j < 4; ++j)
        ob[(16 * w2 + 4 * hi + j) * 18 + rr] = f2bf(acc4[j]);
    }
    // drain staged loads + copy-out stores + LDS; barrier
    asm volatile("s_waitcnt vmcnt(0) lgkmcnt(0)" ::: "memory");
    __builtin_amdgcn_s_barrier();
    __builtin_amdgcn_sched_barrier(0);
  }
#undef STAGE

  // final chunk's o
  if (t < 128) {
    const u16x8 ov = *reinterpret_cast<const u16x8*>(&ob[(t >> 1) * 18 + (t & 1) * 8]);
    *reinterpret_cast<u16x8*>(uv_o + rowbase0 +
        (size_t)((NCH - 1) * CH + (t >> 1)) * D_ + (t & 1) * 8) = ov;
  }
}

// ---------------------------------------------------------------------------
// per-head RMSNorm (over 128) * onorm_w : bf16 in -> bf16 out
// ---------------------------------------------------------------------------
__global__ __launch_bounds__(256) void rms_onorm_bf16(const us* __restrict__ in,
                                                      const float* __restrict__ w,
                                                      us* __restrict__ out) {
  const int bt = blockIdx.x;
  const int d0 = threadIdx.x * 8;
  const us* p = in + (size_t)bt * D_ + d0;
  const ushort4 a = *reinterpret_cast<const ushort4*>(p);
  const ushort4 b = *reinterpret_cast<const ushort4*>(p + 4);
  float v[8] = {bf2f(a.x), bf2f(a.y), bf2f(a.z), bf2f(a.w),
                bf2f(b.x), bf2f(b.y), bf2f(b.z), bf2f(b.w)};
  float ss = 0.f;
#pragma unroll
  for (int j = 0; j < 8; ++j) ss = fmaf(v[j], v[j], ss);
  ss += __shfl_xor(ss, 1);
  ss += __shfl_xor(ss, 2);
  ss += __shfl_xor(ss, 4);
  ss += __shfl_xor(ss, 8);
  const float sc = rsqrtf(ss * (1.0f / 128.0f) + 1e-5f);
  const int hd = d0 & 127;
  ushort4 o0, o1;
  o0.x = f2bf(v[0] * sc * w[hd + 0]); o0.y = f2bf(v[1] * sc * w[hd + 1]);
  o0.z = f2bf(v[2] * sc * w[hd + 2]); o0.w = f2bf(v[3] * sc * w[hd + 3]);
  o1.x = f2bf(v[4] * sc * w[hd + 4]); o1.y = f2bf(v[5] * sc * w[hd + 5]);
  o1.z = f2bf(v[6] * sc * w[hd + 6]); o1.w = f2bf(v[7] * sc * w[hd + 7]);
  us* op = out + (size_t)bt * D_ + d0;
  *reinterpret_cast<ushort4*>(op) = o0;
  *reinterpret_cast<ushort4*>(op + 4) = o1;
}

// ---------------------------------------------------------------------------
extern "C" void kernel_launch(void* const* d_in, const int* in_sizes, int n_in,
                              void* d_out, int out_size, void* d_ws, size_t ws_size,
                              hipStream_t stream) {
  const float* x  = (const float*)d_in[0];
  const float* Wq = (const float*)d_in[1];
  const float* Wk = (const float*)d_in[2];
  const float* Wv = (const float*)d_in[3];
  const float* Wb = (const float*)d_in[4];
  const float* Wo = (const float*)d_in[5];
  const float* cq = (const float*)d_in[6];
  const float* ck = (const float*)d_in[7];
  const float* cv = (const float*)d_in[8];
  const float* ow = (const float*)d_in[9];
  float* out = (float*)d_out;

  // workspace: 5*NE + D*D bf16 + betaT f32 = 176.7 MB (< 201.8 MB proven floor)
  const size_t NE = (size_t)M_ * D_;
  us* ws   = (us*)d_ws;
  us* gout = ws;              // [M,D] gemm scratch; later attn chunks
  us* qch  = ws + NE;         // q swizzled chunk layout
  us* kch  = ws + 2 * NE;     // k swizzled chunk layout
  us* Wch  = ws + 3 * NE;     // -W swizzled chunk layout
  us* kTch = ws + 4 * NE;     // kT swizzled chunk; after seq: rms-out [M,D]
  us* wt   = ws + 5 * NE;     // [D,D] W^T (reused 4x)
  us* attb = gout;                                      // [2048][64][64]
  float* betaT = (float*)(ws + 5 * NE + (size_t)D_ * D_); // [32][4096] f32 (outside gemm scratch!)
  // d_out as bf16 scratch: xb [0,NE), v/uv/o [NE,2NE)
  us* xb = (us*)d_out;
  us* vb = xb + NE;

  dim3 gg(D_ / 256, M_ / 256);  // 8 x 32 = 256 workgroups; x == N-stripe
  dim3 wg(D_ / 64, D_ / 64);

  x_prep<<<M_, 256, 0, stream>>>(x, Wb, xb, betaT);

  wtrans<<<wg, 256, 0, stream>>>(Wv, wt);
  gemm256<false><<<gg, 512, 0, stream>>>(xb, wt, gout, M_, D_, D_);
  conv_silu_plain<<<M_, 256, 0, stream>>>(gout, cv, vb);

  wtrans<<<wg, 256, 0, stream>>>(Wq, wt);
  gemm256<false><<<gg, 512, 0, stream>>>(xb, wt, gout, M_, D_, D_);
  conv_silu_chunk<<<M_, 256, 0, stream>>>(gout, cq, qch, 2);

  wtrans<<<wg, 256, 0, stream>>>(Wk, wt);
  gemm256<false><<<gg, 512, 0, stream>>>(xb, wt, gout, M_, D_, D_);
  conv_silu_chunk<<<M_, 256, 0, stream>>>(gout, ck, kch, 1);

  delta_prep<<<32 * NCH, 256, 0, stream>>>(qch, kch, betaT, vb, Wch, kTch, attb);
  delta_seq<<<256, 512, 0, stream>>>(qch, Wch, kTch, attb, vb);

  rms_onorm_bf16<<<M_, 256, 0, stream>>>(vb, ow, kTch);

  wtrans<<<wg, 256, 0, stream>>>(Wo, wt);
  gemm256<true><<<gg, 512, 0, stream>>>(kTch, wt, out, M_, D_, D_);
}

// Round 12
// 636.621 us; speedup vs baseline: 1.1117x; 1.1117x over previous
//
#include <hip/hip_runtime.h>
#include <math.h>

#define B_ 2
#define T_ 4096
#define D_ 2048
#define H_ 16
#define DK 128
#define DV 128
#define CH 64
#define M_ (B_ * T_)  // 8192
#define NCH (T_ / CH) // 64 chunks

typedef __attribute__((ext_vector_type(8))) short bfrag;   // 8 bf16
typedef __attribute__((ext_vector_type(4))) float ffrag;   // 4 f32 acc
typedef __attribute__((ext_vector_type(8))) unsigned short u16x8;
typedef unsigned short us;

#define MFMA __builtin_amdgcn_mfma_f32_16x16x32_bf16

__device__ inline us f2bf(float f) {
  union { float f; unsigned u; } v; v.f = f;
  unsigned r = v.u + 0x7fffu + ((v.u >> 16) & 1u);
  return (us)(r >> 16);
}
__device__ inline float bf2f(us u) {
  union { unsigned u; float f; } v; v.u = ((unsigned)u) << 16;
  return v.f;
}

// async global->LDS, 16B per lane (dest = wave-uniform base + lane*16)
__device__ inline void gl_lds16(const us* g, us* l) {
  __builtin_amdgcn_global_load_lds(
      (const __attribute__((address_space(1))) void*)g,
      (__attribute__((address_space(3))) void*)l, 16, 0, 0);
}

// ---------------------------------------------------------------------------
// flat f32 -> bf16 (8 elems/thread)  [proven R4-R9]
// ---------------------------------------------------------------------------
__global__ __launch_bounds__(256) void to_bf16(const float* __restrict__ in,
                                               us* __restrict__ out) {
  const size_t i = ((size_t)blockIdx.x * 256 + threadIdx.x) * 8;
  const float4 a = *reinterpret_cast<const float4*>(in + i);
  const float4 b = *reinterpret_cast<const float4*>(in + i + 4);
  ushort4 o0, o1;
  o0.x = f2bf(a.x); o0.y = f2bf(a.y); o0.z = f2bf(a.z); o0.w = f2bf(a.w);
  o1.x = f2bf(b.x); o1.y = f2bf(b.y); o1.z = f2bf(b.z); o1.w = f2bf(b.w);
  *reinterpret_cast<ushort4*>(out + i) = o0;
  *reinterpret_cast<ushort4*>(out + i + 4) = o1;
}

// ---------------------------------------------------------------------------
// beta = sigmoid(x @ Wb) -> betaT[bh][T]  [proven R9]
// ---------------------------------------------------------------------------
__global__ __launch_bounds__(256) void beta_sigmoid(const float* __restrict__ x,
                                                    const float* __restrict__ Wb,
                                                    float* __restrict__ betaT) {
  const int t = threadIdx.x;
  const int m = blockIdx.x * 4 + (t >> 6);
  const int l = t & 63;
  const int c = l & 15;
  const int s = l >> 4;
  const float* xr = x + (size_t)m * D_;
  const int kb = s * (D_ / 4);
  float acc = 0.f;
  for (int k = 0; k < D_ / 4; ++k)
    acc = fmaf(xr[kb + k], Wb[(size_t)(kb + k) * H_ + c], acc);
  acc += __shfl_xor(acc, 16);
  acc += __shfl_xor(acc, 32);
  if (l < 16) {
    const int b = m >> 12, tt = m & (T_ - 1);
    betaT[((size_t)(b * H_ + c)) * T_ + tt] = 1.f / (1.f + expf(-acc));
  }
}

// ---------------------------------------------------------------------------
// transpose + convert: Wt[n][k] = bf16(W[k][n]), 64x64 tiles
// ---------------------------------------------------------------------------
__global__ __launch_bounds__(256) void wtrans(const float* __restrict__ W,
                                              us* __restrict__ Wt) {
  __shared__ float tile[64][68];
  const int k0 = blockIdx.y * 64, n0 = blockIdx.x * 64;
  const int lr = threadIdx.x >> 4, lc = (threadIdx.x & 15) * 4;
#pragma unroll
  for (int p = 0; p < 4; ++p) {
    const int r = lr + p * 16;
    *reinterpret_cast<float4*>(&tile[r][lc]) =
        *reinterpret_cast<const float4*>(&W[(size_t)(k0 + r) * D_ + n0 + lc]);
  }
  __syncthreads();
#pragma unroll
  for (int p = 0; p < 4; ++p) {
    const int r = lr + p * 16;
    ushort4 o;
    o.x = f2bf(tile[lc + 0][r]); o.y = f2bf(tile[lc + 1][r]);
    o.z = f2bf(tile[lc + 2][r]); o.w = f2bf(tile[lc + 3][r]);
    *reinterpret_cast<ushort4*>(&Wt[(size_t)(n0 + r) * D_ + k0 + lc]) = o;
  }
}

// ---------------------------------------------------------------------------
// gemm256 v2 (proven R9): C[M,N] = A[M,K] @ Bt[N,K]^T (bf16).
// ---------------------------------------------------------------------------
template <bool OUTF32>
__global__ __launch_bounds__(512, 2) void gemm256(const us* __restrict__ A,
                                                  const us* __restrict__ Bt,
                                                  void* __restrict__ Cp,
                                                  int M, int N, int K) {
  __shared__ __align__(16) us lds[2][2][2][256 * 32];  // 128 KiB
  const int t = threadIdx.x, l = t & 63, w = t >> 6;
  const int wm = w >> 2, wn = w & 3;           // 2 x 4 waves
  const int fr = l & 15, hi = l >> 4;
  const int sx = 8 * (hi ^ ((fr >> 1) & 3));   // swizzled frag slot (bf16 units)

  const int m0 = blockIdx.y * 256;
  const int n0 = blockIdx.x * 256;             // XCD stripe (x dim == 8)

  const int srow = t >> 2;
  const int scol = 8 * ((t & 3) ^ ((t >> 3) & 3));
  const us* Ab = A + (size_t)(m0 + srow) * K + scol;
  const us* Bb = Bt + (size_t)(n0 + srow) * K + scol;

  ffrag acc[8][4];
#pragma unroll
  for (int mi = 0; mi < 8; ++mi)
#pragma unroll
    for (int ni = 0; ni < 4; ++ni)
#pragma unroll
      for (int e = 0; e < 4; ++e) acc[mi][ni][e] = 0.f;

#define STG_A(bf, kk, kt)                                                      \
  do {                                                                         \
    gl_lds16(Ab + (size_t)(kt) * 64 + (kk) * 32, &lds[bf][0][kk][t * 8]);      \
    gl_lds16(Ab + (size_t)128 * K + (size_t)(kt) * 64 + (kk) * 32,             \
             &lds[bf][0][kk][4096 + t * 8]);                                   \
  } while (0)
#define STG_B(bf, kk, kt)                                                      \
  do {                                                                         \
    gl_lds16(Bb + (size_t)(kt) * 64 + (kk) * 32, &lds[bf][1][kk][t * 8]);      \
    gl_lds16(Bb + (size_t)128 * K + (size_t)(kt) * 64 + (kk) * 32,             \
             &lds[bf][1][kk][4096 + t * 8]);                                   \
  } while (0)

  const int NT = K >> 6;
  STG_A(0, 0, 0); STG_B(0, 0, 0); STG_A(0, 1, 0); STG_B(0, 1, 0);
  asm volatile("s_waitcnt vmcnt(4)" ::: "memory");
  __builtin_amdgcn_s_barrier();
  __builtin_amdgcn_sched_barrier(0);

  const int arow = wm * 128 + fr;
  const int brow = wn * 64 + fr;

#pragma unroll 1
  for (int kt = 0; kt < NT; ++kt) {
    const int cur = kt & 1, oth = cur ^ 1;
    const bool pf = (kt + 1 < NT);
    bfrag af4[4], bf4[4];

    // ======== kk = 0 ========
    {
      const us* pa = &lds[cur][0][0][0];
      const us* pb = &lds[cur][1][0][0];
#pragma unroll
      for (int ni = 0; ni < 4; ++ni)
        bf4[ni] = *reinterpret_cast<const bfrag*>(pb + (brow + ni * 16) * 32 + sx);
#pragma unroll
      for (int mi = 0; mi < 4; ++mi)
        af4[mi] = *reinterpret_cast<const bfrag*>(pa + (arow + mi * 16) * 32 + sx);
      if (pf) STG_A(oth, 0, kt + 1);
      __builtin_amdgcn_s_setprio(1);
#pragma unroll
      for (int mi = 0; mi < 4; ++mi)
#pragma unroll
        for (int ni = 0; ni < 4; ++ni)
          acc[mi][ni] = MFMA(af4[mi], bf4[ni], acc[mi][ni], 0, 0, 0);
      __builtin_amdgcn_s_setprio(0);
#pragma unroll
      for (int mi = 0; mi < 4; ++mi)
        af4[mi] = *reinterpret_cast<const bfrag*>(pa + (arow + 64 + mi * 16) * 32 + sx);
      if (pf) STG_B(oth, 0, kt + 1);
      __builtin_amdgcn_s_setprio(1);
#pragma unroll
      for (int mi = 0; mi < 4; ++mi)
#pragma unroll
        for (int ni = 0; ni < 4; ++ni)
          acc[mi + 4][ni] = MFMA(af4[mi], bf4[ni], acc[mi + 4][ni], 0, 0, 0);
      __builtin_amdgcn_s_setprio(0);
    }
    if (pf) asm volatile("s_waitcnt vmcnt(4)" ::: "memory");
    else    asm volatile("s_waitcnt vmcnt(0)" ::: "memory");
    __builtin_amdgcn_s_barrier();
    __builtin_amdgcn_sched_barrier(0);

    // ======== kk = 1 ========
    {
      const us* pa = &lds[cur][0][1][0];
      const us* pb = &lds[cur][1][1][0];
#pragma unroll
      for (int ni = 0; ni < 4; ++ni)
        bf4[ni] = *reinterpret_cast<const bfrag*>(pb + (brow + ni * 16) * 32 + sx);
#pragma unroll
      for (int mi = 0; mi < 4; ++mi)
        af4[mi] = *reinterpret_cast<const bfrag*>(pa + (arow + mi * 16) * 32 + sx);
      if (pf) STG_A(oth, 1, kt + 1);
      __builtin_amdgcn_s_setprio(1);
#pragma unroll
      for (int mi = 0; mi < 4; ++mi)
#pragma unroll
        for (int ni = 0; ni < 4; ++ni)
          acc[mi][ni] = MFMA(af4[mi], bf4[ni], acc[mi][ni], 0, 0, 0);
      __builtin_amdgcn_s_setprio(0);
#pragma unroll
      for (int mi = 0; mi < 4; ++mi)
        af4[mi] = *reinterpret_cast<const bfrag*>(pa + (arow + 64 + mi * 16) * 32 + sx);
      if (pf) STG_B(oth, 1, kt + 1);
      __builtin_amdgcn_s_setprio(1);
#pragma unroll
      for (int mi = 0; mi < 4; ++mi)
#pragma unroll
        for (int ni = 0; ni < 4; ++ni)
          acc[mi + 4][ni] = MFMA(af4[mi], bf4[ni], acc[mi + 4][ni], 0, 0, 0);
      __builtin_amdgcn_s_setprio(0);
    }
    if (pf) asm volatile("s_waitcnt vmcnt(4)" ::: "memory");
    else    asm volatile("s_waitcnt vmcnt(0)" ::: "memory");
    __builtin_amdgcn_s_barrier();
    __builtin_amdgcn_sched_barrier(0);
  }
#undef STG_A
#undef STG_B

  const int crow = m0 + wm * 128 + hi * 4;
  const int ccol = n0 + wn * 64 + fr;
#pragma unroll
  for (int mi = 0; mi < 8; ++mi)
#pragma unroll
    for (int ni = 0; ni < 4; ++ni)
#pragma unroll
      for (int j = 0; j < 4; ++j) {
        const size_t idx = (size_t)(crow + mi * 16 + j) * N + ccol + ni * 16;
        if constexpr (OUTF32) ((float*)Cp)[idx] = acc[mi][ni][j];
        else ((us*)Cp)[idx] = f2bf(acc[mi][ni][j]);
      }
}

// ---------------------------------------------------------------------------
// conv+silu bodies
// ---------------------------------------------------------------------------
__device__ inline void conv_body(const us* __restrict__ in, const float* cw,
                                 int bt, int d0, int mode, float v[8]) {
  const int tb = bt & (T_ - 1);
  const us* row = in + (size_t)bt * D_ + d0;
#pragma unroll
  for (int j = 0; j < 8; ++j) v[j] = 0.f;
#pragma unroll
  for (int j = 0; j < 4; ++j) {
    if (tb >= j) {
      const us* rp = row - (size_t)(j * D_);
      const ushort4 a = *reinterpret_cast<const ushort4*>(rp);
      const ushort4 b = *reinterpret_cast<const ushort4*>(rp + 4);
      const float wj = cw[3 - j];
      v[0] = fmaf(wj, bf2f(a.x), v[0]); v[1] = fmaf(wj, bf2f(a.y), v[1]);
      v[2] = fmaf(wj, bf2f(a.z), v[2]); v[3] = fmaf(wj, bf2f(a.w), v[3]);
      v[4] = fmaf(wj, bf2f(b.x), v[4]); v[5] = fmaf(wj, bf2f(b.y), v[5]);
      v[6] = fmaf(wj, bf2f(b.z), v[6]); v[7] = fmaf(wj, bf2f(b.w), v[7]);
    }
  }
#pragma unroll
  for (int j = 0; j < 8; ++j) v[j] = v[j] / (1.f + expf(-v[j]));
  if (mode) {
    float ss = 0.f;
#pragma unroll
    for (int j = 0; j < 8; ++j) ss = fmaf(v[j], v[j], ss);
    ss += __shfl_xor(ss, 1);
    ss += __shfl_xor(ss, 2);
    ss += __shfl_xor(ss, 4);
    ss += __shfl_xor(ss, 8);
    float sc = rsqrtf(ss + 1e-6f);
    if (mode == 2) sc *= 0.08838834764831845f;  // 128^-0.5
#pragma unroll
    for (int j = 0; j < 8; ++j) v[j] *= sc;
  }
}

__global__ __launch_bounds__(256) void conv_silu_plain(const us* __restrict__ in,
                                                       const float* __restrict__ cw,
                                                       us* __restrict__ out) {
  const int bt = blockIdx.x, d0 = threadIdx.x * 8;
  float v[8];
  conv_body(in, cw, bt, d0, 0, v);
  ushort4 o0, o1;
  o0.x = f2bf(v[0]); o0.y = f2bf(v[1]); o0.z = f2bf(v[2]); o0.w = f2bf(v[3]);
  o1.x = f2bf(v[4]); o1.y = f2bf(v[5]); o1.z = f2bf(v[6]); o1.w = f2bf(v[7]);
  us* op = out + (size_t)bt * D_ + d0;
  *reinterpret_cast<ushort4*>(op) = o0;
  *reinterpret_cast<ushort4*>(op + 4) = o1;
}

// conv+silu+l2norm -> swizzled chunk layout [bh][cid][64][128], 16B-group XOR(r&15)
__global__ __launch_bounds__(256) void conv_silu_chunk(const us* __restrict__ in,
                                                       const float* __restrict__ cw,
                                                       us* __restrict__ out,
                                                       int mode) {
  const int bt = blockIdx.x, d0 = threadIdx.x * 8;
  float v[8];
  conv_body(in, cw, bt, d0, mode, v);
  const int b = bt >> 12, tt = bt & (T_ - 1);
  const int cid = tt >> 6, r = tt & 63;
  const int h = d0 >> 7, g = (d0 & 127) >> 3;
  us* dst = out + ((size_t)((b * H_ + h) * NCH + cid)) * (CH * DK) +
            r * 128 + ((g ^ (r & 15)) * 8);
  ushort4 o0, o1;
  o0.x = f2bf(v[0]); o0.y = f2bf(v[1]); o0.z = f2bf(v[2]); o0.w = f2bf(v[3]);
  o1.x = f2bf(v[4]); o1.y = f2bf(v[5]); o1.z = f2bf(v[6]); o1.w = f2bf(v[7]);
  *reinterpret_cast<ushort4*>(dst) = o0;
  *reinterpret_cast<ushort4*>(dst + 4) = o1;
}

// ---------------------------------------------------------------------------
// f32 blocked product step for T = M^-1
// ---------------------------------------------------------------------------
__device__ inline void prod_step(float* Tf, const float* Am, float* xbuf,
                                 int r, int c, int I, int J,
                                 int nk, int K0, int K1, int K2) {
  float X = 0.f;
  const int Ks[3] = {K0, K1, K2};
  for (int kk = 0; kk < nk; ++kk) {
    const int K = Ks[kk];
    const float* amrow = Am + (16 * I + r) * 72 + 16 * K;
    const float* tcol = Tf + (16 * K) * 68 + 16 * J + c;
#pragma unroll
    for (int m = 0; m < 16; ++m) X = fmaf(amrow[m], tcol[m * 68], X);
  }
  __syncthreads();
  xbuf[r * 17 + c] = X;
  __syncthreads();
  float s = 0.f;
  const float* trow = Tf + (16 * I + r) * 68 + 16 * I;
#pragma unroll
  for (int m = 0; m < 16; ++m) s = fmaf(trow[m], xbuf[m * 17 + c], s);
  Tf[(16 * I + r) * 68 + 16 * J + c] = -s;
  __syncthreads();
}

// ---------------------------------------------------------------------------
// delta_prep v2 (proven R6): block per (b,h,chunk) = 2048, 256 thr, 2 blocks/CU.
// ---------------------------------------------------------------------------
__global__ __launch_bounds__(256, 2) void delta_prep(const us* __restrict__ qch,
                                                     const us* __restrict__ kch,
                                                     const float* __restrict__ betaT,
                                                     us* __restrict__ v_uv,
                                                     us* __restrict__ Wout,
                                                     us* __restrict__ kTout,
                                                     us* __restrict__ Aout) {
  __shared__ __align__(16) unsigned char lds[72000];
  us*    ks    = (us*)(lds);             // [64*128] swz     (P0-P1)
  us*    Tb    = (us*)(lds);             // [64][72] bf16    (P5-)
  float* Am    = (float*)(lds + 16384);  // [64][72] f32     (P1-P4)
  us*    vTb   = (us*)(lds + 16384);     // [128][72] bf16   (P5-)
  float* Tf    = (float*)(lds + 34816);  // [64][68] f32     (P2-P5)
  us*    atst  = (us*)(lds + 34816);     // attn stage [64*64] (P0-P2)
  us*    Wst   = (us*)(lds + 34816);     // W stage [64*128] (P6-)
  us*    kTb   = (us*)(lds + 52224);     // [128][72] bf16   (P1-P6a)
  us*    UVst  = (us*)(lds + 52224);     // [64*128]         (P6b-)
  float* betac = (float*)(lds + 70656);  // [64]
  float* xbuf  = (float*)(lds + 70912);  // [16][17]

  const int t = threadIdx.x, w = t >> 6, l = t & 63;
  const int rr = l & 15, hi = l >> 4;
  const int bx = blockIdx.x;
  const int bh = bx >> 6, cid = bx & 63;
  const int b = bh >> 4, h = bh & 15;
  const size_t rowbase = ((size_t)b * T_ + (size_t)cid * CH) * D_ + (size_t)h * DK;
  const size_t cbase = (size_t)bx * (CH * DK);
  const size_t abase = (size_t)bx * (CH * CH);

  // ---- P0
  {
    const us* kg = kch + cbase;
#pragma unroll
    for (int p = 0; p < 4; ++p)
      gl_lds16(kg + p * 2048 + t * 8, ks + p * 2048 + t * 8);
    const float4 z = make_float4(0.f, 0.f, 0.f, 0.f);
    *reinterpret_cast<float4*>(atst + t * 16) = z;
    *reinterpret_cast<float4*>(atst + t * 16 + 8) = z;
    if (t < 64) betac[t] = betaT[(size_t)bh * T_ + cid * CH + t];
  }
  __syncthreads();

  // ---- P1
  {
    bfrag qf[4], kf[4];
#pragma unroll
    for (int k4 = 0; k4 < 4; ++k4) {
      const int go = ((4 * k4 + hi) ^ rr) * 8;
      qf[k4] = *reinterpret_cast<const bfrag*>(qch + cbase + (16 * w + rr) * 128 + go);
      kf[k4] = *reinterpret_cast<const bfrag*>(ks + (16 * w + rr) * 128 + go);
    }
    for (int jt = 0; jt <= w; ++jt) {
      ffrag accA = {0.f, 0.f, 0.f, 0.f}, accQ = {0.f, 0.f, 0.f, 0.f};
#pragma unroll
      for (int k4 = 0; k4 < 4; ++k4) {
        const bfrag bfr = *reinterpret_cast<const bfrag*>(
            ks + (16 * jt + rr) * 128 + (((4 * k4 + hi) ^ rr) * 8));
        accA = MFMA(kf[k4], bfr, accA, 0, 0, 0);
        accQ = MFMA(qf[k4], bfr, accQ, 0, 0, 0);
      }
#pragma unroll
      for (int j4 = 0; j4 < 4; ++j4) {
        const int i = 16 * w + 4 * hi + j4, j = 16 * jt + rr;
        Am[i * 72 + j] = (j < i) ? betac[i] * accA[j4] : 0.f;
        if (j <= i)
          atst[i * 64 + (((j >> 3) ^ (i & 7)) * 8) + (j & 7)] = f2bf(accQ[j4]);
      }
    }
    const int r = t & 63, part = t >> 6;
#pragma unroll
    for (int gi = 0; gi < 4; ++gi) {
      const int g = 4 * part + gi;
      const u16x8 kv = *reinterpret_cast<const u16x8*>(ks + r * 128 + ((g ^ (r & 15)) * 8));
#pragma unroll
      for (int j = 0; j < 8; ++j) kTb[(g * 8 + j) * 72 + r] = kv[j];
    }
  }
  __syncthreads();

  // ---- P2
  {
#pragma unroll
    for (int p = 0; p < 2; ++p) {
      const int unit = t + p * 256;
      *reinterpret_cast<u16x8*>(Aout + abase + unit * 8) =
          *reinterpret_cast<const u16x8*>(atst + unit * 8);
    }
#pragma unroll
    for (int p = 0; p < 4; ++p) {
      const int unit = t + p * 256;
      const int d = unit >> 3, sg = unit & 7;
      *reinterpret_cast<u16x8*>(kTout + cbase + unit * 8) =
          *reinterpret_cast<const u16x8*>(kTb + d * 72 + ((sg ^ (d & 7)) * 8));
    }
  }
  __syncthreads();
  for (int i = t; i < 64 * 68; i += 256) Tf[i] = 0.f;
  __syncthreads();

  // ---- P3
  if (t < 64) {
    const int blk = t >> 4, j = t & 15, bd = blk * 16;
    Tf[(bd + j) * 68 + bd + j] = 1.f;
    for (int i = j + 1; i < 16; ++i) {
      float s = 0.f;
      for (int m = j; m < i; ++m)
        s = fmaf(Am[(bd + i) * 72 + bd + m], Tf[(bd + m) * 68 + bd + j], s);
      Tf[(bd + i) * 68 + bd + j] = -s;
    }
  }
  __syncthreads();

  // ---- P4
  {
    const int r = t >> 4, c = t & 15;
    prod_step(Tf, Am, xbuf, r, c, 1, 0, 1, 0, 0, 0);
    prod_step(Tf, Am, xbuf, r, c, 2, 0, 2, 0, 1, 0);
    prod_step(Tf, Am, xbuf, r, c, 3, 0, 3, 0, 1, 2);
    prod_step(Tf, Am, xbuf, r, c, 2, 1, 1, 1, 0, 0);
    prod_step(Tf, Am, xbuf, r, c, 3, 1, 2, 1, 2, 0);
    prod_step(Tf, Am, xbuf, r, c, 3, 2, 1, 2, 0, 0);
  }

  // ---- P5
  {
    const int vr = t >> 2, vp = t & 3;
    u16x8 vv[4];
#pragma unroll
    for (int g = 0; g < 4; ++g)
      vv[g] = *reinterpret_cast<const u16x8*>(v_uv + rowbase + (size_t)vr * D_ +
                                              vp * 32 + g * 8);
    const int ti = t >> 2, tg = t & 3;
    u16x8 w0, w1;
#pragma unroll
    for (int jj = 0; jj < 8; ++jj) {
      const int j0 = tg * 16 + jj, j1 = j0 + 8;
      w0[jj] = f2bf(Tf[ti * 68 + j0] * betac[j0]);
      w1[jj] = f2bf(Tf[ti * 68 + j1] * betac[j1]);
    }
    *reinterpret_cast<u16x8*>(Tb + ti * 72 + tg * 16) = w0;
    *reinterpret_cast<u16x8*>(Tb + ti * 72 + tg * 16 + 8) = w1;
#pragma unroll
    for (int g = 0; g < 4; ++g)
#pragma unroll
      for (int j = 0; j < 8; ++j)
        vTb[(vp * 32 + g * 8 + j) * 72 + vr] = vv[g][j];
  }
  __syncthreads();

  // ---- P6a
  {
    bfrag ta[2];
#pragma unroll
    for (int k2 = 0; k2 < 2; ++k2)
      ta[k2] = *reinterpret_cast<const bfrag*>(Tb + (16 * w + rr) * 72 + 32 * k2 + 8 * hi);
#pragma unroll
    for (int dt = 0; dt < 8; ++dt) {
      ffrag acc = {0.f, 0.f, 0.f, 0.f};
#pragma unroll
      for (int k2 = 0; k2 < 2; ++k2) {
        const bfrag bfr = *reinterpret_cast<const bfrag*>(
            kTb + (16 * dt + rr) * 72 + 32 * k2 + 8 * hi);
        acc = MFMA(ta[k2], bfr, acc, 0, 0, 0);
      }
#pragma unroll
      for (int j4 = 0; j4 < 4; ++j4) {
        const int i = 16 * w + 4 * hi + j4, d = 16 * dt + rr;
        Wst[i * 128 + (((d >> 3) ^ (i & 15)) * 8) + (d & 7)] = f2bf(-acc[j4]);
      }
    }
  }
  __syncthreads();

  // ---- P6b
  {
    bfrag ta[2];
#pragma unroll
    for (int k2 = 0; k2 < 2; ++k2)
      ta[k2] = *reinterpret_cast<const bfrag*>(Tb + (16 * w + rr) * 72 + 32 * k2 + 8 * hi);
#pragma unroll
    for (int et = 0; et < 8; ++et) {
      ffrag acc = {0.f, 0.f, 0.f, 0.f};
#pragma unroll
      for (int k2 = 0; k2 < 2; ++k2) {
        const bfrag bfr = *reinterpret_cast<const bfrag*>(
            vTb + (16 * et + rr) * 72 + 32 * k2 + 8 * hi);
        acc = MFMA(ta[k2], bfr, acc, 0, 0, 0);
      }
#pragma unroll
      for (int j4 = 0; j4 < 4; ++j4)
        UVst[(16 * w + 4 * hi + j4) * 128 + 16 * et + rr] = f2bf(acc[j4]);
    }
#pragma unroll
    for (int p = 0; p < 4; ++p) {
      const int unit = t + p * 256;
      *reinterpret_cast<u16x8*>(Wout + cbase + unit * 8) =
          *reinterpret_cast<const u16x8*>(Wst + unit * 8);
    }
  }
  __syncthreads();

  // ---- P7
#pragma unroll
  for (int p = 0; p < 4; ++p) {
    const int unit = t + p * 256;
    const int r = unit >> 4, g = unit & 15;
    *reinterpret_cast<u16x8*>(v_uv + rowbase + (size_t)r * D_ + g * 8) =
        *reinterpret_cast<const u16x8*>(UVst + r * 128 + g * 8);
  }
}

// ---------------------------------------------------------------------------
// delta_seq v4 (kept from R10): 512 thr, role-split phases, coalesced o.
// ---------------------------------------------------------------------------
__global__ __launch_bounds__(512, 1) void delta_seq(const us* __restrict__ qch,
                                                    const us* __restrict__ Wch,
                                                    const us* __restrict__ kTch,
                                                    const us* __restrict__ atch,
                                                    us* __restrict__ uv_o) {
  __shared__ __align__(16) us qs[2][CH * DK];    // 16KB x2
  __shared__ __align__(16) us Ws[2][CH * DK];    // 16KB x2
  __shared__ __align__(16) us kTs[2][DK * CH];   // 16KB x2
  __shared__ __align__(16) us ats[2][CH * CH];   // 8KB  x2
  __shared__ __align__(16) us uvs[2][CH * 16];   // 2KB  x2
  __shared__ __align__(16) us Sb[2][16 * 136];   // 4.25KB x2 (S^T bf16, dbuf)
  __shared__ __align__(16) us ub[CH * 18];       // 2.25KB (u bf16)
  __shared__ __align__(16) us ob[CH * 18];       // 2.25KB (o bf16 stage)

  const int t = threadIdx.x, l = t & 63, w = t >> 6;
  const int bx = blockIdx.x;
  const int vs = bx >> 5, bh = bx & 31;
  const int b = bh >> 4, h = bh & 15;
  const int rr = l & 15, hi = l >> 4;
  const int w2 = w & 3;  // tile index within role group

  ffrag sacc[2];
#pragma unroll
  for (int t2 = 0; t2 < 2; ++t2)
#pragma unroll
    for (int j = 0; j < 4; ++j) sacc[t2][j] = 0.f;

  for (int i = t; i < 16 * 136; i += 512) Sb[0][i] = 0;

  const size_t cbQ = (size_t)(bh * NCH) * (CH * DK);
  const size_t cbA = (size_t)(bh * NCH) * (CH * CH);
  const size_t rowbase0 = ((size_t)b * T_) * D_ + (size_t)h * DK + vs * 16;

#define STAGE(buf, cid)                                                        \
  do {                                                                         \
    const us* qg = qch + cbQ + (size_t)(cid) * (CH * DK);                      \
    const us* Wg = Wch + cbQ + (size_t)(cid) * (CH * DK);                      \
    const us* kg = kTch + cbQ + (size_t)(cid) * (CH * DK);                     \
    const us* ag = atch + cbA + (size_t)(cid) * (CH * CH);                     \
    gl_lds16(qg + t * 8, &qs[buf][t * 8]);                                     \
    gl_lds16(qg + 4096 + t * 8, &qs[buf][4096 + t * 8]);                       \
    gl_lds16(Wg + t * 8, &Ws[buf][t * 8]);                                     \
    gl_lds16(Wg + 4096 + t * 8, &Ws[buf][4096 + t * 8]);                       \
    gl_lds16(kg + t * 8, &kTs[buf][t * 8]);                                    \
    gl_lds16(kg + 4096 + t * 8, &kTs[buf][4096 + t * 8]);                      \
    gl_lds16(ag + t * 8, &ats[buf][t * 8]);                                    \
    if (t < 128)                                                               \
      gl_lds16(uv_o + rowbase0 + (size_t)((cid) * CH + (t >> 1)) * D_ + (t & 1) * 8, \
               &uvs[buf][t * 8]);                                              \
  } while (0)

  STAGE(0, 0);
  asm volatile("s_waitcnt vmcnt(0) lgkmcnt(0)" ::: "memory");
  __builtin_amdgcn_s_barrier();
  __builtin_amdgcn_sched_barrier(0);

  for (int cid = 0; cid < NCH; ++cid) {
    const int cur = cid & 1;

    // coalesced copy-out of previous chunk's o (ob stable until phase B)
    if (cid > 0 && t < 128) {
      const u16x8 ov = *reinterpret_cast<const u16x8*>(&ob[(t >> 1) * 18 + (t & 1) * 8]);
      *reinterpret_cast<u16x8*>(uv_o + rowbase0 +
          (size_t)((cid - 1) * CH + (t >> 1)) * D_ + (t & 1) * 8) = ov;
    }
    if (cid + 1 < NCH) STAGE(cur ^ 1, cid + 1);  // async; drained at end barrier

    bfrag sbf[4];
#pragma unroll
    for (int ks = 0; ks < 4; ++ks)
      sbf[ks] = *reinterpret_cast<const bfrag*>(&Sb[cur][rr * 136 + ks * 32 + hi * 8]);

    ffrag acc4;
    if (w < 4) {
      // ---- phase A (u): rows 16w..16w+15
#pragma unroll
      for (int j = 0; j < 4; ++j)
        acc4[j] = bf2f(uvs[cur][(16 * w + 4 * hi + j) * 16 + rr]);
#pragma unroll
      for (int ks = 0; ks < 4; ++ks) {
        const bfrag af = *reinterpret_cast<const bfrag*>(
            &Ws[cur][(16 * w + rr) * 128 + (((4 * ks + hi) ^ rr) * 8)]);
        acc4 = MFMA(af, sbf[ks], acc4, 0, 0, 0);
      }
#pragma unroll
      for (int j = 0; j < 4; ++j)
        ub[(16 * w + 4 * hi + j) * 18 + rr] = f2bf(acc4[j]);
    } else {
      // ---- phase A (o partial = q.Sb): rows 16w2..16w2+15
#pragma unroll
      for (int j = 0; j < 4; ++j) acc4[j] = 0.f;
#pragma unroll
      for (int ks = 0; ks < 4; ++ks) {
        const bfrag af = *reinterpret_cast<const bfrag*>(
            &qs[cur][(16 * w2 + rr) * 128 + (((4 * ks + hi) ^ rr) * 8)]);
        acc4 = MFMA(af, sbf[ks], acc4, 0, 0, 0);
      }
    }
    asm volatile("s_waitcnt lgkmcnt(0)" ::: "memory");  // ub visible; VM loads in flight
    __builtin_amdgcn_s_barrier();
    __builtin_amdgcn_sched_barrier(0);

    if (w < 4) {
      // ---- phase B (S-update): tiles 2w, 2w+1
      bfrag ubf[2];
#pragma unroll
      for (int ks = 0; ks < 2; ++ks)
#pragma unroll
        for (int j = 0; j < 8; ++j)
          ubf[ks][j] = (short)ub[(32 * ks + 8 * hi + j) * 18 + rr];
#pragma unroll
      for (int t2 = 0; t2 < 2; ++t2) {
        const int tile = 2 * w + t2;
#pragma unroll
        for (int ks = 0; ks < 2; ++ks) {
          const bfrag af = *reinterpret_cast<const bfrag*>(
              &kTs[cur][(16 * tile + rr) * 64 + (((4 * ks + hi) ^ (rr & 7)) * 8)]);
          sacc[t2] = MFMA(af, ubf[ks], sacc[t2], 0, 0, 0);
        }
        ushort4 sw;
        sw.x = f2bf(sacc[t2][0]); sw.y = f2bf(sacc[t2][1]);
        sw.z = f2bf(sacc[t2][2]); sw.w = f2bf(sacc[t2][3]);
        *reinterpret_cast<ushort4*>(&Sb[cur ^ 1][rr * 136 + 16 * tile + 4 * hi]) = sw;
      }
    } else {
      // ---- phase B (o finish = + attn.u): rows 16w2..16w2+15
      const int nks = (w2 < 2) ? 1 : 2;  // causal: upper attn cols are zero
      for (int ks = 0; ks < nks; ++ks) {
        bfrag ubf;
#pragma unroll
        for (int j = 0; j < 8; ++j)
          ubf[j] = (short)ub[(32 * ks + 8 * hi + j) * 18 + rr];
        const bfrag af = *reinterpret_cast<const bfrag*>(
            &ats[cur][(16 * w2 + rr) * 64 + (((4 * ks + hi) ^ (rr & 7)) * 8)]);
        acc4 = MFMA(af, ubf, acc4, 0, 0, 0);
      }
#pragma unroll
      for (int j = 0; j < 4; ++j)
        ob[(16 * w2 + 4 * hi + j) * 18 + rr] = f2bf(acc4[j]);
    }
    // drain staged loads + copy-out stores + LDS; barrier
    asm volatile("s_waitcnt vmcnt(0) lgkmcnt(0)" ::: "memory");
    __builtin_amdgcn_s_barrier();
    __builtin_amdgcn_sched_barrier(0);
  }
#undef STAGE

  // final chunk's o
  if (t < 128) {
    const u16x8 ov = *reinterpret_cast<const u16x8*>(&ob[(t >> 1) * 18 + (t & 1) * 8]);
    *reinterpret_cast<u16x8*>(uv_o + rowbase0 +
        (size_t)((NCH - 1) * CH + (t >> 1)) * D_ + (t & 1) * 8) = ov;
  }
}

// ---------------------------------------------------------------------------
// per-head RMSNorm (over 128) * onorm_w : bf16 in -> bf16 out
// ---------------------------------------------------------------------------
__global__ __launch_bounds__(256) void rms_onorm_bf16(const us* __restrict__ in,
                                                      const float* __restrict__ w,
                                                      us* __restrict__ out) {
  const int bt = blockIdx.x;
  const int d0 = threadIdx.x * 8;
  const us* p = in + (size_t)bt * D_ + d0;
  const ushort4 a = *reinterpret_cast<const ushort4*>(p);
  const ushort4 b = *reinterpret_cast<const ushort4*>(p + 4);
  float v[8] = {bf2f(a.x), bf2f(a.y), bf2f(a.z), bf2f(a.w),
                bf2f(b.x), bf2f(b.y), bf2f(b.z), bf2f(b.w)};
  float ss = 0.f;
#pragma unroll
  for (int j = 0; j < 8; ++j) ss = fmaf(v[j], v[j], ss);
  ss += __shfl_xor(ss, 1);
  ss += __shfl_xor(ss, 2);
  ss += __shfl_xor(ss, 4);
  ss += __shfl_xor(ss, 8);
  const float sc = rsqrtf(ss * (1.0f / 128.0f) + 1e-5f);
  const int hd = d0 & 127;
  ushort4 o0, o1;
  o0.x = f2bf(v[0] * sc * w[hd + 0]); o0.y = f2bf(v[1] * sc * w[hd + 1]);
  o0.z = f2bf(v[2] * sc * w[hd + 2]); o0.w = f2bf(v[3] * sc * w[hd + 3]);
  o1.x = f2bf(v[4] * sc * w[hd + 4]); o1.y = f2bf(v[5] * sc * w[hd + 5]);
  o1.z = f2bf(v[6] * sc * w[hd + 6]); o1.w = f2bf(v[7] * sc * w[hd + 7]);
  us* op = out + (size_t)bt * D_ + d0;
  *reinterpret_cast<ushort4*>(op) = o0;
  *reinterpret_cast<ushort4*>(op + 4) = o1;
}

// ---------------------------------------------------------------------------
extern "C" void kernel_launch(void* const* d_in, const int* in_sizes, int n_in,
                              void* d_out, int out_size, void* d_ws, size_t ws_size,
                              hipStream_t stream) {
  const float* x  = (const float*)d_in[0];
  const float* Wq = (const float*)d_in[1];
  const float* Wk = (const float*)d_in[2];
  const float* Wv = (const float*)d_in[3];
  const float* Wb = (const float*)d_in[4];
  const float* Wo = (const float*)d_in[5];
  const float* cq = (const float*)d_in[6];
  const float* ck = (const float*)d_in[7];
  const float* cv = (const float*)d_in[8];
  const float* ow = (const float*)d_in[9];
  float* out = (float*)d_out;

  // workspace: 5*NE + D*D bf16 + betaT f32 = 176.7 MB (< 201.8 MB proven floor)
  const size_t NE = (size_t)M_ * D_;
  us* ws   = (us*)d_ws;
  us* gout = ws;              // [M,D] gemm scratch; later attn chunks
  us* qch  = ws + NE;         // q swizzled chunk layout
  us* kch  = ws + 2 * NE;     // k swizzled chunk layout
  us* Wch  = ws + 3 * NE;     // -W swizzled chunk layout
  us* kTch = ws + 4 * NE;     // kT swizzled chunk; after seq: rms-out [M,D]
  us* wt   = ws + 5 * NE;     // [D,D] W^T (reused 4x)
  us* attb = gout;                                      // [2048][64][64]
  float* betaT = (float*)(ws + 5 * NE + (size_t)D_ * D_); // [32][4096] f32
  // d_out as bf16 scratch: xb [0,NE), v/uv/o [NE,2NE)
  us* xb = (us*)d_out;
  us* vb = xb + NE;

  dim3 gg(D_ / 256, M_ / 256);  // 8 x 32 = 256 workgroups; x == N-stripe
  dim3 wg(D_ / 64, D_ / 64);

  to_bf16<<<NE / 2048, 256, 0, stream>>>(x, xb);

  wtrans<<<wg, 256, 0, stream>>>(Wv, wt);
  gemm256<false><<<gg, 512, 0, stream>>>(xb, wt, gout, M_, D_, D_);
  conv_silu_plain<<<M_, 256, 0, stream>>>(gout, cv, vb);

  wtrans<<<wg, 256, 0, stream>>>(Wq, wt);
  gemm256<false><<<gg, 512, 0, stream>>>(xb, wt, gout, M_, D_, D_);
  conv_silu_chunk<<<M_, 256, 0, stream>>>(gout, cq, qch, 2);

  wtrans<<<wg, 256, 0, stream>>>(Wk, wt);
  gemm256<false><<<gg, 512, 0, stream>>>(xb, wt, gout, M_, D_, D_);
  conv_silu_chunk<<<M_, 256, 0, stream>>>(gout, ck, kch, 1);

  beta_sigmoid<<<M_ / 4, 256, 0, stream>>>(x, Wb, betaT);

  delta_prep<<<32 * NCH, 256, 0, stream>>>(qch, kch, betaT, vb, Wch, kTch, attb);
  delta_seq<<<256, 512, 0, stream>>>(qch, Wch, kTch, attb, vb);

  rms_onorm_bf16<<<M_, 256, 0, stream>>>(vb, ow, kTch);

  wtrans<<<wg, 256, 0, stream>>>(Wo, wt);
  gemm256<true><<<gg, 512, 0, stream>>>(kTch, wt, out, M_, D_, D_);
}